// Round 8
// baseline (403.544 us; speedup 1.0000x reference)
//
#include <hip/hip_runtime.h>
#include <math.h>

#define N_NODES 100000
#define N_EDGES 1000000
#define HID 64
#define OUT_DIM 32
#define NUM_GRAPHS 512
#define CAP 48  // max in-degree capacity; deg ~ Poisson(10), P(any overflow) ~ 1e-13

typedef __attribute__((ext_vector_type(4))) float f4v;
typedef __attribute__((ext_vector_type(8))) short s8v;  // 8 bf16 in 4 VGPRs

// fp32 -> bf16 (RNE) and back, as raw shorts
static __device__ inline short f2bf(float f) {
  unsigned u = __float_as_uint(f);
  unsigned r = (u + 0x7fffu + ((u >> 16) & 1u)) >> 16;
  return (short)r;
}
static __device__ inline float bf2f(short s) {
  return __uint_as_float(((unsigned)(unsigned short)s) << 16);
}

// ---------------------------------------------------------------------------
// CSR build, phase-partitioned for L2 write-combining.
// Each block stages its edge chunk in LDS, then sweeps 13 dst-partitions
// (dst>>13) in phases. All resident blocks progress in rough lockstep, so
// writes to a given 1.5 MB csr partition cluster temporally -> a node's csr
// line collects its ~10 slot-writes in L2 before eviction (was: 1 evict per
// write, WRITE_SIZE 59.7 MB for 4 MB payload).
// ---------------------------------------------------------------------------
#define CSR_CHUNK 4096

__global__ __launch_bounds__(256) void csr_fill_kernel(
    const int* __restrict__ ei, int* __restrict__ deg, int* __restrict__ csr,
    int n_edges) {
  __shared__ int s_src[CSR_CHUNK];
  __shared__ int s_dst[CSR_CHUNK];
  int e0 = blockIdx.x * CSR_CHUNK;
  int n = n_edges - e0;
  if (n > CSR_CHUNK) n = CSR_CHUNK;
  for (int i = threadIdx.x; i < n; i += 256) {
    s_src[i] = ei[e0 + i];
    s_dst[i] = ei[n_edges + e0 + i];
  }
  __syncthreads();
  for (int p = 0; p <= (N_NODES >> 13); p++) {  // 13 partitions of 8192 nodes
    for (int i = threadIdx.x; i < n; i += 256) {
      int dst = s_dst[i];
      if ((dst >> 13) == p) {
        int slot = atomicAdd(&deg[dst], 1);
        if (slot < CAP) csr[dst * CAP + slot] = s_src[i];
      }
    }
    __syncthreads();  // keep the block in phase
  }
}

// ---------------------------------------------------------------------------
// Graph ranges: starts[g] = lower_bound(batch, g); batch is sorted.
// ---------------------------------------------------------------------------
__global__ __launch_bounds__(256) void starts_kernel(
    const int* __restrict__ batch, int* __restrict__ starts) {
  int g = blockIdx.x * blockDim.x + threadIdx.x;
  if (g > NUM_GRAPHS) return;
  int lo = 0, hi = N_NODES;
  while (lo < hi) {
    int mid = (lo + hi) >> 1;
    if (batch[mid] < g) lo = mid + 1; else hi = mid;
  }
  starts[g] = lo;
}

// ---------------------------------------------------------------------------
// Weight prep (all 4 weight matrices in one launch):
// W [K=64][N=64] fp32 -> transposed bf16 hi/lo tables [N][K]
// wtab layout: which*8192 + {0:hi, 4096:lo}
// ---------------------------------------------------------------------------
__global__ __launch_bounds__(256) void wprep4_kernel(
    const float* __restrict__ W1a, const float* __restrict__ W2a,
    const float* __restrict__ W1b, const float* __restrict__ W2b,
    short* __restrict__ wtab) {
  int t = blockIdx.x * blockDim.x + threadIdx.x;
  if (t >= 4 * HID * HID) return;
  int which = t >> 12;
  int r = t & 4095;
  const float* W = (which == 0) ? W1a : (which == 1) ? W2a : (which == 2) ? W1b : W2b;
  short* hiT = wtab + which * 8192;
  short* loT = hiT + 4096;
  int n = r & 63, k = r >> 6;
  float w = W[k * HID + n];
  short h = f2bf(w);
  hiT[n * HID + k] = h;
  loT[n * HID + k] = f2bf(w - bf2f(h));
}

// ---------------------------------------------------------------------------
// Gather (GIN pre-MLP): hbuf[i] = x[i] + sum_{j->i} x[j].
// One wave per node; 4 groups of 16 lanes, each group one f4v row-slice and
// 2 neighbor streams -> 8 independent row loads in flight.
// R3-BUG-SAFE: every __shfl executes unconditionally with all 64 lanes
// active (loop bound uniform in d); only the LOADS are predicated.
// ---------------------------------------------------------------------------
__global__ __launch_bounds__(256) void gather_kernel(
    const float* __restrict__ x, const int* __restrict__ deg,
    const int* __restrict__ csr, float* __restrict__ hbuf, int n_nodes) {
  int lane = threadIdx.x & 63;
  int node = blockIdx.x * (blockDim.x >> 6) + (threadIdx.x >> 6);
  if (node >= n_nodes) return;  // node uniform per wave -> whole wave exits
  int g = lane >> 4;    // neighbor-stream group 0..3
  int sub = lane & 15;  // f4v slice within the 64-dim row

  int d = deg[node];
  if (d > CAP) d = CAP;
  int idx = (lane < d) ? csr[node * CAP + lane] : 0;  // no shfl here: safe

  const f4v* x4 = (const f4v*)x;
  f4v a0 = (g == 0) ? x4[(size_t)node * 16 + sub] : (f4v){0.f, 0.f, 0.f, 0.f};
  f4v a1 = {0.f, 0.f, 0.f, 0.f};
  for (int j0 = 0; j0 < d; j0 += 8) {  // d uniform: all lanes iterate together
    int ja = j0 + g;                    // <= d-1+3 <= 50 < 64: valid shfl src
    int jb = j0 + 4 + g;                // <= d-1+7 <= 54 < 64
    int sa = __shfl(idx, ja);           // full-wave, unconditional
    int sb = __shfl(idx, jb);           // full-wave, unconditional
    if (ja < d) a0 += x4[(size_t)sa * 16 + sub];  // predicated load only
    if (jb < d) a1 += x4[(size_t)sb * 16 + sub];
  }
  f4v a = a0 + a1;
  // reduce across the 4 groups (all lanes active, uniform control)
  a.x += __shfl_xor(a.x, 16); a.y += __shfl_xor(a.y, 16);
  a.z += __shfl_xor(a.z, 16); a.w += __shfl_xor(a.w, 16);
  a.x += __shfl_xor(a.x, 32); a.y += __shfl_xor(a.y, 32);
  a.z += __shfl_xor(a.z, 32); a.w += __shfl_xor(a.w, 32);
  if (g == 0) ((f4v*)hbuf)[(size_t)node * 16 + sub] = a;
}

// ---------------------------------------------------------------------------
// GIN MLP via MFMA (bf16 hi/lo split, fp32 accumulate). R7-proven.
// ---------------------------------------------------------------------------
#define LPAD 72  // LDS row stride in shorts

__global__ __launch_bounds__(256) void gin_mlp_mfma_kernel(
    const float* __restrict__ hbuf,
    const short* __restrict__ W1hi, const short* __restrict__ W1lo,
    const float* __restrict__ b1,
    const short* __restrict__ W2hi, const short* __restrict__ W2lo,
    const float* __restrict__ b2,
    float* __restrict__ out, int n_nodes, int apply_relu) {
  __shared__ short lds[4][2][16 * LPAD];

  int lane = threadIdx.x & 63;
  int wv = threadIdx.x >> 6;
  int m = lane & 15;
  int quad = lane >> 4;
  int nodeBase = blockIdx.x * 64 + wv * 16;
  int node = nodeBase + m;
  bool valid = node < n_nodes;

  // ---- A fragments: A[m=lane&15][k=quad*8+j] per K=32 block ----
  s8v ahi[2], alo[2];
  for (int kb = 0; kb < 2; kb++) {
    int ks = kb * 32 + quad * 8;
    f4v r0 = {0.f, 0.f, 0.f, 0.f}, r1 = {0.f, 0.f, 0.f, 0.f};
    if (valid) {
      const f4v* hp = (const f4v*)(hbuf + (size_t)node * HID + ks);
      r0 = hp[0];
      r1 = hp[1];
    }
    s8v h, l;
#pragma unroll
    for (int j = 0; j < 8; j++) {
      float v = (j < 4) ? r0[j] : r1[j - 4];
      short hb = f2bf(v);
      h[j] = hb;
      l[j] = f2bf(v - bf2f(hb));
    }
    ahi[kb] = h;
    alo[kb] = l;
  }

  // ---- matmul 1: H = hbuf @ W1 ----
  f4v acc[4];
#pragma unroll
  for (int nt = 0; nt < 4; nt++) acc[nt] = (f4v){0.f, 0.f, 0.f, 0.f};
#pragma unroll
  for (int kb = 0; kb < 2; kb++) {
#pragma unroll
    for (int nt = 0; nt < 4; nt++) {
      int n = nt * 16 + m;
      s8v bh = *(const s8v*)(W1hi + n * HID + kb * 32 + quad * 8);
      s8v bl = *(const s8v*)(W1lo + n * HID + kb * 32 + quad * 8);
      acc[nt] = __builtin_amdgcn_mfma_f32_16x16x32_bf16(ahi[kb], bh, acc[nt], 0, 0, 0);
      acc[nt] = __builtin_amdgcn_mfma_f32_16x16x32_bf16(ahi[kb], bl, acc[nt], 0, 0, 0);
      acc[nt] = __builtin_amdgcn_mfma_f32_16x16x32_bf16(alo[kb], bh, acc[nt], 0, 0, 0);
      acc[nt] = __builtin_amdgcn_mfma_f32_16x16x32_bf16(alo[kb], bl, acc[nt], 0, 0, 0);
    }
  }

  // ---- bias + relu, stage H into LDS (node-row layout, bf16 hi/lo) ----
  short* Lhi = lds[wv][0];
  short* Llo = lds[wv][1];
#pragma unroll
  for (int nt = 0; nt < 4; nt++) {
    int col = nt * 16 + m;
    float bb = b1[col];
#pragma unroll
    for (int r = 0; r < 4; r++) {
      int row = quad * 4 + r;
      float h = fmaxf(acc[nt][r] + bb, 0.f);
      short hb = f2bf(h);
      Lhi[row * LPAD + col] = hb;
      Llo[row * LPAD + col] = f2bf(h - bf2f(hb));
    }
  }
  __syncthreads();

  // ---- re-frag H as A-operand ----
  s8v a2hi[2], a2lo[2];
#pragma unroll
  for (int kb = 0; kb < 2; kb++) {
    int off = m * LPAD + kb * 32 + quad * 8;
    a2hi[kb] = *(const s8v*)(Lhi + off);
    a2lo[kb] = *(const s8v*)(Llo + off);
  }

  // ---- matmul 2: OUT = H @ W2 ----
  f4v acc2[4];
#pragma unroll
  for (int nt = 0; nt < 4; nt++) acc2[nt] = (f4v){0.f, 0.f, 0.f, 0.f};
#pragma unroll
  for (int kb = 0; kb < 2; kb++) {
#pragma unroll
    for (int nt = 0; nt < 4; nt++) {
      int n = nt * 16 + m;
      s8v bh = *(const s8v*)(W2hi + n * HID + kb * 32 + quad * 8);
      s8v bl = *(const s8v*)(W2lo + n * HID + kb * 32 + quad * 8);
      acc2[nt] = __builtin_amdgcn_mfma_f32_16x16x32_bf16(a2hi[kb], bh, acc2[nt], 0, 0, 0);
      acc2[nt] = __builtin_amdgcn_mfma_f32_16x16x32_bf16(a2hi[kb], bl, acc2[nt], 0, 0, 0);
      acc2[nt] = __builtin_amdgcn_mfma_f32_16x16x32_bf16(a2lo[kb], bh, acc2[nt], 0, 0, 0);
      acc2[nt] = __builtin_amdgcn_mfma_f32_16x16x32_bf16(a2lo[kb], bl, acc2[nt], 0, 0, 0);
    }
  }

  // ---- epilogue: bias (+relu), store ----
#pragma unroll
  for (int nt = 0; nt < 4; nt++) {
    int col = nt * 16 + m;
    float bb = b2[col];
#pragma unroll
    for (int r = 0; r < 4; r++) {
      int row = quad * 4 + r;
      int onode = nodeBase + row;
      if (onode < n_nodes) {
        float o = acc2[nt][r] + bb;
        if (apply_relu) o = fmaxf(o, 0.f);
        out[(size_t)onode * HID + col] = o;
      }
    }
  }
}

// ---------------------------------------------------------------------------
// Pooling: one wave per graph (batch sorted -> contiguous range). No atomics.
// No cross-lane ops inside the (group-divergent) loop; reduce after.
// ---------------------------------------------------------------------------
__global__ __launch_bounds__(256) void pool_kernel(
    const float* __restrict__ emb, const int* __restrict__ starts,
    float* __restrict__ sums) {
  int lane = threadIdx.x & 63;
  int g = blockIdx.x * 4 + (threadIdx.x >> 6);  // 512 waves total
  int group = lane >> 4, sub = lane & 15;
  int s0 = starts[g], s1 = starts[g + 1];

  const f4v* e4 = (const f4v*)emb;
  f4v acc = {0.f, 0.f, 0.f, 0.f};
  for (int n = s0 + group; n < s1; n += 4) {
    f4v v = e4[(size_t)n * 16 + sub];
    v.x = fmaxf(v.x, 0.f); v.y = fmaxf(v.y, 0.f);
    v.z = fmaxf(v.z, 0.f); v.w = fmaxf(v.w, 0.f);
    acc += v;
  }
  acc.x += __shfl_xor(acc.x, 16); acc.y += __shfl_xor(acc.y, 16);
  acc.z += __shfl_xor(acc.z, 16); acc.w += __shfl_xor(acc.w, 16);
  acc.x += __shfl_xor(acc.x, 32); acc.y += __shfl_xor(acc.y, 32);
  acc.z += __shfl_xor(acc.z, 32); acc.w += __shfl_xor(acc.w, 32);
  if (lane < 16) ((f4v*)sums)[g * 16 + sub] = acc;
}

// ---------------------------------------------------------------------------
// Head: pooled = sums/max(cnt,1); o = (pooled@Wp1+bp1)@Wp2+bp2; log_softmax.
// One wave per graph; all shfl wave-uniform.
// ---------------------------------------------------------------------------
__global__ __launch_bounds__(64) void head_kernel(
    const float* __restrict__ sums, const int* __restrict__ starts,
    const float* __restrict__ Wp1, const float* __restrict__ bp1,
    const float* __restrict__ Wp2, const float* __restrict__ bp2,
    float* __restrict__ out) {
  int g = blockIdx.x;
  int lane = threadIdx.x;  // 0..63
  float c = fmaxf((float)(starts[g + 1] - starts[g]), 1.0f);
  float p = sums[g * HID + lane] / c;

  float t = bp1[lane];
#pragma unroll
  for (int k = 0; k < HID; k++) {
    t += __shfl(p, k) * Wp1[k * HID + lane];
  }

  float acc = 0.0f;
#pragma unroll
  for (int k = 0; k < HID; k++) {
    float tk = __shfl(t, k);
    if (lane < OUT_DIM) acc += tk * Wp2[k * OUT_DIM + lane];
  }
  float o = (lane < OUT_DIM) ? (acc + bp2[lane]) : -1e30f;

  float m = o;
#pragma unroll
  for (int off = 32; off >= 1; off >>= 1) m = fmaxf(m, __shfl_xor(m, off));
  float ex = (lane < OUT_DIM) ? expf(o - m) : 0.0f;
  float s = ex;
#pragma unroll
  for (int off = 32; off >= 1; off >>= 1) s += __shfl_xor(s, off);
  float lse = m + logf(s);
  if (lane < OUT_DIM) out[g * OUT_DIM + lane] = o - lse;
}

extern "C" void kernel_launch(void* const* d_in, const int* in_sizes, int n_in,
                              void* d_out, int out_size, void* d_ws, size_t ws_size,
                              hipStream_t stream) {
  const float* x   = (const float*)d_in[0];
  const int* ei    = (const int*)d_in[1];
  const int* batch = (const int*)d_in[2];
  const float* W1a = (const float*)d_in[3];
  const float* b1a = (const float*)d_in[4];
  const float* W2a = (const float*)d_in[5];
  const float* b2a = (const float*)d_in[6];
  const float* W1b = (const float*)d_in[7];
  const float* b1b = (const float*)d_in[8];
  const float* W2b = (const float*)d_in[9];
  const float* b2b = (const float*)d_in[10];
  const float* Wp1 = (const float*)d_in[11];
  const float* bp1 = (const float*)d_in[12];
  const float* Wp2 = (const float*)d_in[13];
  const float* bp2 = (const float*)d_in[14];

  float* emb    = (float*)d_out;                          // [N_NODES, HID]
  float* logits = (float*)d_out + (size_t)N_NODES * HID;  // [NUM_GRAPHS, OUT_DIM]
  float* x1 = emb;  // layer-0 output staged in d_out; overwritten by emb

  // ws: hbuf | deg | csr | starts | sums | wtab  (~45.4 MB, proven scale)
  float* hbuf  = (float*)d_ws;
  int* deg     = (int*)(hbuf + (size_t)N_NODES * HID);
  int* csr     = deg + N_NODES;
  int* starts  = csr + (size_t)N_NODES * CAP;
  float* sums  = (float*)(starts + NUM_GRAPHS + 1);
  short* wtab  = (short*)(sums + NUM_GRAPHS * HID);
  short* W1aHi = wtab + 0 * 4096; short* W1aLo = wtab + 1 * 4096;
  short* W2aHi = wtab + 2 * 4096; short* W2aLo = wtab + 3 * 4096;
  short* W1bHi = wtab + 4 * 4096; short* W1bLo = wtab + 5 * 4096;
  short* W2bHi = wtab + 6 * 4096; short* W2bLo = wtab + 7 * 4096;

  // ----- weight prep (bf16 hi/lo, transposed; one launch for all 4) -----
  wprep4_kernel<<<64, 256, 0, stream>>>(W1a, W2a, W1b, W2b, wtab);

  // ----- graph ranges + inverse adjacency -----
  starts_kernel<<<3, 256, 0, stream>>>(batch, starts);
  hipMemsetAsync(deg, 0, N_NODES * sizeof(int), stream);
  csr_fill_kernel<<<(N_EDGES + CSR_CHUNK - 1) / CSR_CHUNK, 256, 0, stream>>>(
      ei, deg, csr, N_EDGES);

  int gather_blocks = (N_NODES + 3) / 4;  // 4 waves (nodes) per block
  int mlp_blocks = (N_NODES + 63) / 64;

  // ----- layer 0: hbuf = x + agg(x); x1 = relu(MLP_a(hbuf)) -----
  gather_kernel<<<gather_blocks, 256, 0, stream>>>(x, deg, csr, hbuf, N_NODES);
  gin_mlp_mfma_kernel<<<mlp_blocks, 256, 0, stream>>>(
      hbuf, W1aHi, W1aLo, b1a, W2aHi, W2aLo, b2a, x1, N_NODES, /*relu=*/1);

  // ----- layer 1: hbuf = x1 + agg(x1); emb = MLP_b(hbuf) (pre-ReLU) -----
  gather_kernel<<<gather_blocks, 256, 0, stream>>>(x1, deg, csr, hbuf, N_NODES);
  gin_mlp_mfma_kernel<<<mlp_blocks, 256, 0, stream>>>(
      hbuf, W1bHi, W1bLo, b1b, W2bHi, W2bLo, b2b, emb, N_NODES, /*relu=*/0);

  // ----- pooling: one wave per graph, no atomics -----
  pool_kernel<<<NUM_GRAPHS / 4, 256, 0, stream>>>(emb, starts, sums);

  // ----- head -----
  head_kernel<<<NUM_GRAPHS, 64, 0, stream>>>(sums, starts, Wp1, bp1, Wp2, bp2, logits);
}

// Round 9
// 377.779 us; speedup vs baseline: 1.0682x; 1.0682x over previous
//
#include <hip/hip_runtime.h>
#include <math.h>

#define N_NODES 100000
#define N_EDGES 1000000
#define HID 64
#define OUT_DIM 32
#define NUM_GRAPHS 512
#define CAP 48    // max in-degree capacity; deg ~ Poisson(10)
#define NBUCK 98  // dst >> 10 -> 0..97
#define BCAP 11264  // bucket capacity; mean 10204, sd ~101 -> 10+ sigma margin
#define ACHUNK 4096

typedef __attribute__((ext_vector_type(4))) float f4v;
typedef __attribute__((ext_vector_type(8))) short s8v;  // 8 bf16 in 4 VGPRs

// fp32 -> bf16 (RNE) and back, as raw shorts
static __device__ inline short f2bf(float f) {
  unsigned u = __float_as_uint(f);
  unsigned r = (u + 0x7fffu + ((u >> 16) & 1u)) >> 16;
  return (short)r;
}
static __device__ inline float bf2f(short s) {
  return __uint_as_float(((unsigned)(unsigned short)s) << 16);
}

// ---------------------------------------------------------------------------
// CSR build pass A: radix-partition edges into 98 dst-buckets.
// Block counting-sorts its 4096-edge chunk in LDS, then flushes contiguous
// per-bucket runs (one global cursor atomicAdd per bucket per block).
// Turns 1M scattered 4B writes (= 1M line writebacks, 60 MB) into ~4.4 MB
// of dense append-stream writes.
// ---------------------------------------------------------------------------
__global__ __launch_bounds__(256) void bucket_kernel(
    const int* __restrict__ ei, int* __restrict__ bedge,
    int* __restrict__ bcnt, int n_edges) {
  __shared__ int s_pack[ACHUNK];
  __shared__ unsigned char s_b[ACHUNK];
  __shared__ int s_sorted[ACHUNK];
  __shared__ int s_hist[NBUCK];
  __shared__ int s_off[NBUCK];
  __shared__ int s_base[NBUCK];

  int e0 = blockIdx.x * ACHUNK;
  int n = n_edges - e0;
  if (n > ACHUNK) n = ACHUNK;

  for (int i = threadIdx.x; i < NBUCK; i += 256) s_hist[i] = 0;
  __syncthreads();

  for (int i = threadIdx.x; i < n; i += 256) {
    int src = ei[e0 + i];
    int dst = ei[n_edges + e0 + i];
    int b = dst >> 10;
    s_pack[i] = src | ((dst & 1023) << 17);  // src:17b | dstLocal:10b
    s_b[i] = (unsigned char)b;
    atomicAdd(&s_hist[b], 1);
  }
  __syncthreads();

  if (threadIdx.x == 0) {  // exclusive scan over 98 buckets (tiny, serial)
    int run = 0;
    for (int b = 0; b < NBUCK; b++) { s_off[b] = run; run += s_hist[b]; }
  }
  if (threadIdx.x < NBUCK) {  // reserve global space per bucket
    int c = s_hist[threadIdx.x];
    s_base[threadIdx.x] = c > 0 ? atomicAdd(&bcnt[threadIdx.x], c) : 0;
  }
  __syncthreads();

  for (int i = threadIdx.x; i < n; i += 256) {  // LDS scatter (sort)
    int p = atomicAdd(&s_off[s_b[i]], 1);
    s_sorted[p] = s_pack[i];
  }
  __syncthreads();

  for (int b = 0; b < NBUCK; b++) {  // flush contiguous runs
    int cnt = s_hist[b];
    if (cnt == 0) continue;
    int start = s_off[b] - cnt;  // s_off[b] is now end offset
    int gbase = s_base[b];
    for (int i = threadIdx.x; i < cnt; i += 256) {
      int idx = gbase + i;
      if (idx < BCAP) bedge[b * BCAP + idx] = s_sorted[start + i];
    }
  }
}

// ---------------------------------------------------------------------------
// CSR build pass B: one block per bucket. All writes confined to the
// bucket's 197 KB csr slice + 4 KB deg slice -> stays in ONE XCD's L2
// until the block finishes; writeback = dirty lines only.
// ---------------------------------------------------------------------------
__global__ __launch_bounds__(256) void csr_from_buckets_kernel(
    const int* __restrict__ bedge, const int* __restrict__ bcnt,
    int* __restrict__ deg, int* __restrict__ csr) {
  int b = blockIdx.x;
  int n = bcnt[b];
  if (n > BCAP) n = BCAP;
  for (int i = threadIdx.x; i < n; i += 256) {
    int e = bedge[b * BCAP + i];
    int src = e & 0x1FFFF;
    int dst = (b << 10) | (e >> 17);
    int slot = atomicAdd(&deg[dst], 1);
    if (slot < CAP) csr[dst * CAP + slot] = src;
  }
}

// ---------------------------------------------------------------------------
// Graph ranges: starts[g] = lower_bound(batch, g); batch is sorted.
// ---------------------------------------------------------------------------
__global__ __launch_bounds__(256) void starts_kernel(
    const int* __restrict__ batch, int* __restrict__ starts) {
  int g = blockIdx.x * blockDim.x + threadIdx.x;
  if (g > NUM_GRAPHS) return;
  int lo = 0, hi = N_NODES;
  while (lo < hi) {
    int mid = (lo + hi) >> 1;
    if (batch[mid] < g) lo = mid + 1; else hi = mid;
  }
  starts[g] = lo;
}

// ---------------------------------------------------------------------------
// Weight prep (all 4 matrices, one launch):
// W [K=64][N=64] fp32 -> transposed bf16 hi/lo tables [N][K]
// ---------------------------------------------------------------------------
__global__ __launch_bounds__(256) void wprep4_kernel(
    const float* __restrict__ W1a, const float* __restrict__ W2a,
    const float* __restrict__ W1b, const float* __restrict__ W2b,
    short* __restrict__ wtab) {
  int t = blockIdx.x * blockDim.x + threadIdx.x;
  if (t >= 4 * HID * HID) return;
  int which = t >> 12;
  int r = t & 4095;
  const float* W = (which == 0) ? W1a : (which == 1) ? W2a : (which == 2) ? W1b : W2b;
  short* hiT = wtab + which * 8192;
  short* loT = hiT + 4096;
  int n = r & 63, k = r >> 6;
  float w = W[k * HID + n];
  short h = f2bf(w);
  hiT[n * HID + k] = h;
  loT[n * HID + k] = f2bf(w - bf2f(h));
}

// ---------------------------------------------------------------------------
// Gather (GIN pre-MLP): hbuf[i] = x[i] + sum_{j->i} x[j].
// One wave per node; 4 groups of 16 lanes, 2 streams/group -> 8 loads in
// flight. R3-BUG-SAFE: every __shfl executes unconditionally with all 64
// lanes active; only the loads are predicated.
// ---------------------------------------------------------------------------
__global__ __launch_bounds__(256) void gather_kernel(
    const float* __restrict__ x, const int* __restrict__ deg,
    const int* __restrict__ csr, float* __restrict__ hbuf, int n_nodes) {
  int lane = threadIdx.x & 63;
  int node = blockIdx.x * (blockDim.x >> 6) + (threadIdx.x >> 6);
  if (node >= n_nodes) return;  // node uniform per wave -> whole wave exits
  int g = lane >> 4;
  int sub = lane & 15;

  int d = deg[node];
  if (d > CAP) d = CAP;
  int idx = (lane < d) ? csr[node * CAP + lane] : 0;

  const f4v* x4 = (const f4v*)x;
  f4v a0 = (g == 0) ? x4[(size_t)node * 16 + sub] : (f4v){0.f, 0.f, 0.f, 0.f};
  f4v a1 = {0.f, 0.f, 0.f, 0.f};
  for (int j0 = 0; j0 < d; j0 += 8) {  // d uniform: all lanes iterate together
    int ja = j0 + g;
    int jb = j0 + 4 + g;
    int sa = __shfl(idx, ja);  // full-wave, unconditional
    int sb = __shfl(idx, jb);
    if (ja < d) a0 += x4[(size_t)sa * 16 + sub];  // predicated load only
    if (jb < d) a1 += x4[(size_t)sb * 16 + sub];
  }
  f4v a = a0 + a1;
  a.x += __shfl_xor(a.x, 16); a.y += __shfl_xor(a.y, 16);
  a.z += __shfl_xor(a.z, 16); a.w += __shfl_xor(a.w, 16);
  a.x += __shfl_xor(a.x, 32); a.y += __shfl_xor(a.y, 32);
  a.z += __shfl_xor(a.z, 32); a.w += __shfl_xor(a.w, 32);
  if (g == 0) ((f4v*)hbuf)[(size_t)node * 16 + sub] = a;
}

// ---------------------------------------------------------------------------
// GIN MLP via MFMA (bf16 hi/lo split, fp32 accumulate). R7-proven.
// ---------------------------------------------------------------------------
#define LPAD 72  // LDS row stride in shorts

__global__ __launch_bounds__(256) void gin_mlp_mfma_kernel(
    const float* __restrict__ hbuf,
    const short* __restrict__ W1hi, const short* __restrict__ W1lo,
    const float* __restrict__ b1,
    const short* __restrict__ W2hi, const short* __restrict__ W2lo,
    const float* __restrict__ b2,
    float* __restrict__ out, int n_nodes, int apply_relu) {
  __shared__ short lds[4][2][16 * LPAD];

  int lane = threadIdx.x & 63;
  int wv = threadIdx.x >> 6;
  int m = lane & 15;
  int quad = lane >> 4;
  int nodeBase = blockIdx.x * 64 + wv * 16;
  int node = nodeBase + m;
  bool valid = node < n_nodes;

  s8v ahi[2], alo[2];
  for (int kb = 0; kb < 2; kb++) {
    int ks = kb * 32 + quad * 8;
    f4v r0 = {0.f, 0.f, 0.f, 0.f}, r1 = {0.f, 0.f, 0.f, 0.f};
    if (valid) {
      const f4v* hp = (const f4v*)(hbuf + (size_t)node * HID + ks);
      r0 = hp[0];
      r1 = hp[1];
    }
    s8v h, l;
#pragma unroll
    for (int j = 0; j < 8; j++) {
      float v = (j < 4) ? r0[j] : r1[j - 4];
      short hb = f2bf(v);
      h[j] = hb;
      l[j] = f2bf(v - bf2f(hb));
    }
    ahi[kb] = h;
    alo[kb] = l;
  }

  f4v acc[4];
#pragma unroll
  for (int nt = 0; nt < 4; nt++) acc[nt] = (f4v){0.f, 0.f, 0.f, 0.f};
#pragma unroll
  for (int kb = 0; kb < 2; kb++) {
#pragma unroll
    for (int nt = 0; nt < 4; nt++) {
      int n = nt * 16 + m;
      s8v bh = *(const s8v*)(W1hi + n * HID + kb * 32 + quad * 8);
      s8v bl = *(const s8v*)(W1lo + n * HID + kb * 32 + quad * 8);
      acc[nt] = __builtin_amdgcn_mfma_f32_16x16x32_bf16(ahi[kb], bh, acc[nt], 0, 0, 0);
      acc[nt] = __builtin_amdgcn_mfma_f32_16x16x32_bf16(ahi[kb], bl, acc[nt], 0, 0, 0);
      acc[nt] = __builtin_amdgcn_mfma_f32_16x16x32_bf16(alo[kb], bh, acc[nt], 0, 0, 0);
      acc[nt] = __builtin_amdgcn_mfma_f32_16x16x32_bf16(alo[kb], bl, acc[nt], 0, 0, 0);
    }
  }

  short* Lhi = lds[wv][0];
  short* Llo = lds[wv][1];
#pragma unroll
  for (int nt = 0; nt < 4; nt++) {
    int col = nt * 16 + m;
    float bb = b1[col];
#pragma unroll
    for (int r = 0; r < 4; r++) {
      int row = quad * 4 + r;
      float h = fmaxf(acc[nt][r] + bb, 0.f);
      short hb = f2bf(h);
      Lhi[row * LPAD + col] = hb;
      Llo[row * LPAD + col] = f2bf(h - bf2f(hb));
    }
  }
  __syncthreads();

  s8v a2hi[2], a2lo[2];
#pragma unroll
  for (int kb = 0; kb < 2; kb++) {
    int off = m * LPAD + kb * 32 + quad * 8;
    a2hi[kb] = *(const s8v*)(Lhi + off);
    a2lo[kb] = *(const s8v*)(Llo + off);
  }

  f4v acc2[4];
#pragma unroll
  for (int nt = 0; nt < 4; nt++) acc2[nt] = (f4v){0.f, 0.f, 0.f, 0.f};
#pragma unroll
  for (int kb = 0; kb < 2; kb++) {
#pragma unroll
    for (int nt = 0; nt < 4; nt++) {
      int n = nt * 16 + m;
      s8v bh = *(const s8v*)(W2hi + n * HID + kb * 32 + quad * 8);
      s8v bl = *(const s8v*)(W2lo + n * HID + kb * 32 + quad * 8);
      acc2[nt] = __builtin_amdgcn_mfma_f32_16x16x32_bf16(a2hi[kb], bh, acc2[nt], 0, 0, 0);
      acc2[nt] = __builtin_amdgcn_mfma_f32_16x16x32_bf16(a2hi[kb], bl, acc2[nt], 0, 0, 0);
      acc2[nt] = __builtin_amdgcn_mfma_f32_16x16x32_bf16(a2lo[kb], bh, acc2[nt], 0, 0, 0);
      acc2[nt] = __builtin_amdgcn_mfma_f32_16x16x32_bf16(a2lo[kb], bl, acc2[nt], 0, 0, 0);
    }
  }

#pragma unroll
  for (int nt = 0; nt < 4; nt++) {
    int col = nt * 16 + m;
    float bb = b2[col];
#pragma unroll
    for (int r = 0; r < 4; r++) {
      int row = quad * 4 + r;
      int onode = nodeBase + row;
      if (onode < n_nodes) {
        float o = acc2[nt][r] + bb;
        if (apply_relu) o = fmaxf(o, 0.f);
        out[(size_t)onode * HID + col] = o;
      }
    }
  }
}

// ---------------------------------------------------------------------------
// Pooling: one wave per graph (batch sorted -> contiguous range). No atomics.
// ---------------------------------------------------------------------------
__global__ __launch_bounds__(256) void pool_kernel(
    const float* __restrict__ emb, const int* __restrict__ starts,
    float* __restrict__ sums) {
  int lane = threadIdx.x & 63;
  int g = blockIdx.x * 4 + (threadIdx.x >> 6);
  int group = lane >> 4, sub = lane & 15;
  int s0 = starts[g], s1 = starts[g + 1];

  const f4v* e4 = (const f4v*)emb;
  f4v acc = {0.f, 0.f, 0.f, 0.f};
  for (int n = s0 + group; n < s1; n += 4) {
    f4v v = e4[(size_t)n * 16 + sub];
    v.x = fmaxf(v.x, 0.f); v.y = fmaxf(v.y, 0.f);
    v.z = fmaxf(v.z, 0.f); v.w = fmaxf(v.w, 0.f);
    acc += v;
  }
  acc.x += __shfl_xor(acc.x, 16); acc.y += __shfl_xor(acc.y, 16);
  acc.z += __shfl_xor(acc.z, 16); acc.w += __shfl_xor(acc.w, 16);
  acc.x += __shfl_xor(acc.x, 32); acc.y += __shfl_xor(acc.y, 32);
  acc.z += __shfl_xor(acc.z, 32); acc.w += __shfl_xor(acc.w, 32);
  if (lane < 16) ((f4v*)sums)[g * 16 + sub] = acc;
}

// ---------------------------------------------------------------------------
// Head: pooled = sums/max(cnt,1); o = (pooled@Wp1+bp1)@Wp2+bp2; log_softmax.
// ---------------------------------------------------------------------------
__global__ __launch_bounds__(64) void head_kernel(
    const float* __restrict__ sums, const int* __restrict__ starts,
    const float* __restrict__ Wp1, const float* __restrict__ bp1,
    const float* __restrict__ Wp2, const float* __restrict__ bp2,
    float* __restrict__ out) {
  int g = blockIdx.x;
  int lane = threadIdx.x;
  float c = fmaxf((float)(starts[g + 1] - starts[g]), 1.0f);
  float p = sums[g * HID + lane] / c;

  float t = bp1[lane];
#pragma unroll
  for (int k = 0; k < HID; k++) {
    t += __shfl(p, k) * Wp1[k * HID + lane];
  }

  float acc = 0.0f;
#pragma unroll
  for (int k = 0; k < HID; k++) {
    float tk = __shfl(t, k);
    if (lane < OUT_DIM) acc += tk * Wp2[k * OUT_DIM + lane];
  }
  float o = (lane < OUT_DIM) ? (acc + bp2[lane]) : -1e30f;

  float m = o;
#pragma unroll
  for (int off = 32; off >= 1; off >>= 1) m = fmaxf(m, __shfl_xor(m, off));
  float ex = (lane < OUT_DIM) ? expf(o - m) : 0.0f;
  float s = ex;
#pragma unroll
  for (int off = 32; off >= 1; off >>= 1) s += __shfl_xor(s, off);
  float lse = m + logf(s);
  if (lane < OUT_DIM) out[g * OUT_DIM + lane] = o - lse;
}

extern "C" void kernel_launch(void* const* d_in, const int* in_sizes, int n_in,
                              void* d_out, int out_size, void* d_ws, size_t ws_size,
                              hipStream_t stream) {
  const float* x   = (const float*)d_in[0];
  const int* ei    = (const int*)d_in[1];
  const int* batch = (const int*)d_in[2];
  const float* W1a = (const float*)d_in[3];
  const float* b1a = (const float*)d_in[4];
  const float* W2a = (const float*)d_in[5];
  const float* b2a = (const float*)d_in[6];
  const float* W1b = (const float*)d_in[7];
  const float* b1b = (const float*)d_in[8];
  const float* W2b = (const float*)d_in[9];
  const float* b2b = (const float*)d_in[10];
  const float* Wp1 = (const float*)d_in[11];
  const float* bp1 = (const float*)d_in[12];
  const float* Wp2 = (const float*)d_in[13];
  const float* bp2 = (const float*)d_in[14];

  float* emb    = (float*)d_out;                          // [N_NODES, HID]
  float* logits = (float*)d_out + (size_t)N_NODES * HID;  // [NUM_GRAPHS, OUT_DIM]
  float* x1 = emb;  // layer-0 output staged in d_out; overwritten by emb

  // ws: hbuf | deg | csr | starts | sums | wtab  (~45.4 MB, proven scale)
  float* hbuf  = (float*)d_ws;
  int* deg     = (int*)(hbuf + (size_t)N_NODES * HID);
  int* csr     = deg + N_NODES;
  int* starts  = csr + (size_t)N_NODES * CAP;
  float* sums  = (float*)(starts + NUM_GRAPHS + 1);
  short* wtab  = (short*)(sums + NUM_GRAPHS * HID);
  short* W1aHi = wtab + 0 * 4096; short* W1aLo = wtab + 1 * 4096;
  short* W2aHi = wtab + 2 * 4096; short* W2aLo = wtab + 3 * 4096;
  short* W1bHi = wtab + 4 * 4096; short* W1bLo = wtab + 5 * 4096;
  short* W2bHi = wtab + 6 * 4096; short* W2bLo = wtab + 7 * 4096;

  // transient bucket storage aliased INTO hbuf (used only before 1st gather)
  int* bedge = (int*)hbuf;              // NBUCK*BCAP ints = 4.4 MB < 25.6 MB
  int* bcnt  = bedge + NBUCK * BCAP;    // NBUCK ints

  // ----- weight prep + graph ranges -----
  wprep4_kernel<<<64, 256, 0, stream>>>(W1a, W2a, W1b, W2b, wtab);
  starts_kernel<<<3, 256, 0, stream>>>(batch, starts);

  // ----- inverse adjacency: radix-bucketed 2-pass build -----
  hipMemsetAsync(bcnt, 0, NBUCK * sizeof(int), stream);
  hipMemsetAsync(deg, 0, N_NODES * sizeof(int), stream);
  bucket_kernel<<<(N_EDGES + ACHUNK - 1) / ACHUNK, 256, 0, stream>>>(
      ei, bedge, bcnt, N_EDGES);
  csr_from_buckets_kernel<<<NBUCK, 256, 0, stream>>>(bedge, bcnt, deg, csr);

  int gather_blocks = (N_NODES + 3) / 4;  // 4 waves (nodes) per block
  int mlp_blocks = (N_NODES + 63) / 64;

  // ----- layer 0: hbuf = x + agg(x); x1 = relu(MLP_a(hbuf)) -----
  gather_kernel<<<gather_blocks, 256, 0, stream>>>(x, deg, csr, hbuf, N_NODES);
  gin_mlp_mfma_kernel<<<mlp_blocks, 256, 0, stream>>>(
      hbuf, W1aHi, W1aLo, b1a, W2aHi, W2aLo, b2a, x1, N_NODES, /*relu=*/1);

  // ----- layer 1: hbuf = x1 + agg(x1); emb = MLP_b(hbuf) (pre-ReLU) -----
  gather_kernel<<<gather_blocks, 256, 0, stream>>>(x1, deg, csr, hbuf, N_NODES);
  gin_mlp_mfma_kernel<<<mlp_blocks, 256, 0, stream>>>(
      hbuf, W1bHi, W1bLo, b1b, W2bHi, W2bLo, b2b, emb, N_NODES, /*relu=*/0);

  // ----- pooling + head -----
  pool_kernel<<<NUM_GRAPHS / 4, 256, 0, stream>>>(emb, starts, sums);
  head_kernel<<<NUM_GRAPHS, 64, 0, stream>>>(sums, starts, Wp1, bp1, Wp2, bp2, logits);
}